// Round 12
// baseline (404.875 us; speedup 1.0000x reference)
//
#include <hip/hip_runtime.h>
#include <hip/hip_fp16.h>

#define NEG_SLOPE 0.2f

constexpr int NN = 50000;   // nodes
constexpr int EE = 800000;  // edges (before self loops)

static inline int cdiv(int a, int b) { return (a + b - 1) / b; }

typedef _Float16 h2 __attribute__((ext_vector_type(2)));

#if __has_builtin(__builtin_amdgcn_fdot2)
static __device__ inline float fdot2f(h2 a, h2 b, float c) {
    return __builtin_amdgcn_fdot2(a, b, c, false);
}
#else
static __device__ inline float fdot2f(h2 a, h2 b, float c) {
    return c + (float)a.x * (float)b.x + (float)a.y * (float)b.y;
}
#endif

static __device__ inline h2 bch2(unsigned u) { return __builtin_bit_cast(h2, u); }

// Edge data: split arrays (was 32B padded ERec).
//   ea_arr[slot]  : uint4 = 8 fp16 edge attrs (16B, aligned)
//   src_arr[slot] : int   = source node id
// 40% less record traffic per pass; same load count per edge.

// ================= CSR build =================
__global__ void hist_kernel(const int4* __restrict__ dst4, int* __restrict__ rowcnt, int E4) {
    int t = blockIdx.x * blockDim.x + threadIdx.x;
    if (t >= E4) return;
    int4 d = dst4[t];
    atomicAdd(&rowcnt[d.x], 1);
    atomicAdd(&rowcnt[d.y], 1);
    atomicAdd(&rowcnt[d.z], 1);
    atomicAdd(&rowcnt[d.w], 1);
}

__global__ void scana_kernel(const int* __restrict__ cnt, int* __restrict__ blocksum, int n) {
    __shared__ int s[256];
    int t = threadIdx.x, g = blockIdx.x * 256 + t;
    s[t] = (g < n) ? cnt[g] + 1 : 0;
    __syncthreads();
    for (int off = 128; off > 0; off >>= 1) {
        if (t < off) s[t] += s[t + off];
        __syncthreads();
    }
    if (t == 0) blocksum[blockIdx.x] = s[0];
}

__global__ void scanb_kernel(const int* __restrict__ cnt, const int* __restrict__ blocksum,
                             int nbk, int* __restrict__ rowptr, int* __restrict__ cursor,
                             int* __restrict__ src_arr, int n) {
    __shared__ int bs[256];
    __shared__ int s[256];
    int t = threadIdx.x;
    bs[t] = (t < nbk) ? blocksum[t] : 0;
    __syncthreads();
    for (int off = 1; off < 256; off <<= 1) {
        int tv = (t >= off) ? bs[t - off] : 0; __syncthreads();
        bs[t] += tv; __syncthreads();
    }
    int blockoff = (blockIdx.x > 0) ? bs[blockIdx.x - 1] : 0;
    int g = blockIdx.x * 256 + t;
    int val = (g < n) ? cnt[g] + 1 : 0;
    s[t] = val; __syncthreads();
    for (int off = 1; off < 256; off <<= 1) {
        int tv = (t >= off) ? s[t - off] : 0; __syncthreads();
        s[t] += tv; __syncthreads();
    }
    if (g >= n) return;
    int incl = s[t] + blockoff;
    rowptr[g + 1] = incl;
    int beg = incl - val;
    cursor[g] = beg + 1;          // slot `beg` reserved for the self loop
    src_arr[beg] = g;             // self-loop source
    if (g == 0) rowptr[0] = 0;
}

__global__ void scatter_kernel(const int* __restrict__ src, const int* __restrict__ dst,
                               const float* __restrict__ eattr,
                               int* __restrict__ cursor,
                               uint4* __restrict__ ea_arr, int* __restrict__ src_arr, int E) {
    int t = blockIdx.x * blockDim.x + threadIdx.x;
    if (t >= E) return;
    int d = dst[t];
    int pos = atomicAdd(&cursor[d], 1);
    const float4* ea4 = (const float4*)(eattr + (size_t)t * 8);
    float4 a = ea4[0], b = ea4[1];
    __half2 h0 = __floats2half2_rn(a.x, a.y);
    __half2 h1 = __floats2half2_rn(a.z, a.w);
    __half2 h2v = __floats2half2_rn(b.x, b.y);
    __half2 h3 = __floats2half2_rn(b.z, b.w);
    uint4 u;
    u.x = *(unsigned*)&h0; u.y = *(unsigned*)&h1;
    u.z = *(unsigned*)&h2v; u.w = *(unsigned*)&h3;
    ea_arr[pos] = u;
    src_arr[pos] = src[t];
}

// ======= fused: node_linear layer-1 (blocks < NB1) + loop_sea (rest) =========
template <int NB1>
__global__ __launch_bounds__(256) void fused_nl1_loopsea_kernel(
    const float* __restrict__ x,
    const float* __restrict__ Wl, const float* __restrict__ bl,
    const float* __restrict__ Wr, const float* __restrict__ br,
    __half* __restrict__ xl, __half* __restrict__ xr,
    const int* __restrict__ rowptr, uint4* __restrict__ ea_arr, int n) {
    constexpr int K = 16, CT = 32, NPB = 8;
    __shared__ float Wls[K * CT];
    __shared__ float Wrs[K * CT];
    __shared__ float xs[NPB * K];
    int tid = threadIdx.x;
    if (blockIdx.x < NB1) {
        int ty = tid >> 5, c = tid & 31;
        for (int i = tid; i < K * CT; i += 256) { Wls[i] = Wl[i]; Wrs[i] = Wr[i]; }
        int node0 = blockIdx.x * NPB;
        for (int i = tid; i < NPB * K; i += 256) {
            int nd = node0 + i / K;
            xs[i] = (nd < n) ? x[(size_t)node0 * K + i] : 0.f;
        }
        __syncthreads();
        int node = node0 + ty;
        if (node >= n) return;
        float aL = bl[c], aR = br[c];
        const float* xrow = &xs[ty * K];
        for (int k = 0; k < K; ++k) {
            float xv = xrow[k];
            aL = fmaf(xv, Wls[k * CT + c], aL);
            aR = fmaf(xv, Wrs[k * CT + c], aR);
        }
        xl[(size_t)node * CT + c] = __float2half(aL);
        xr[(size_t)node * CT + c] = __float2half(aR);
    } else {
        int wave = ((blockIdx.x - NB1) * 256 + tid) >> 6;
        int lane = tid & 63;
        if (wave >= n) return;
        int beg = rowptr[wave], end = rowptr[wave + 1];
        int k = lane & 7, j0 = lane >> 3;
        const __half* eap = (const __half*)ea_arr;
        float s = 0.f;
        for (int j = beg + 1 + j0; j < end; j += 8)
            s += __half2float(eap[(unsigned)j * 8 + k]);
        s += __shfl_xor(s, 8); s += __shfl_xor(s, 16); s += __shfl_xor(s, 32);
        int cnt = end - beg - 1;
        if (lane < 8) ((__half*)ea_arr)[(unsigned)beg * 8 + lane] =
            __float2half(s / fmaxf((float)cnt, 1.f));
    }
}

// ======= node linear (fp16 input, fp16 LDS weights, fdot2, node-loop) ========
template <int K, int CT, int NPB>
__global__ __launch_bounds__(256) void node_linear_h_kernel(
    const __half* __restrict__ x,
    const float* __restrict__ Wl, const float* __restrict__ bl,
    const float* __restrict__ Wr, const float* __restrict__ br,
    __half* __restrict__ xl, __half* __restrict__ xr, int n) {
    constexpr int K2 = K / 2;
    constexpr int TS = 256 / CT;     // node-slots per pass
    __shared__ h2 Wls[K2 * CT];
    __shared__ h2 Wrs[K2 * CT];
    __shared__ h2 xs[NPB * K2];
    int tid = threadIdx.x;
    for (int i = tid; i < K2 * CT; i += 256) {
        int k2 = i / CT, c = i % CT;
        Wls[i] = h2{(_Float16)Wl[(2 * k2) * CT + c], (_Float16)Wl[(2 * k2 + 1) * CT + c]};
        Wrs[i] = h2{(_Float16)Wr[(2 * k2) * CT + c], (_Float16)Wr[(2 * k2 + 1) * CT + c]};
    }
    int node0 = blockIdx.x * NPB;
    const unsigned* xg = (const unsigned*)(x + (size_t)node0 * K);
    for (int i = tid; i < NPB * K2; i += 256) {
        int nd = node0 + i / K2;
        unsigned u = (nd < n) ? xg[i] : 0u;
        xs[i] = bch2(u);
    }
    __syncthreads();
    int c = tid % CT, ty = tid / CT;
    int bound = (node0 + NPB < n) ? NPB : (n - node0);
    for (int local = ty; local < bound; local += TS) {
        int node = node0 + local;
        float aL = bl[c], aR = br[c];
        const h2* xrow = &xs[local * K2];
        for (int k = 0; k < K2; ++k) {
            h2 xv = xrow[k];
            aL = fdot2f(xv, Wls[k * CT + c], aL);
            aR = fdot2f(xv, Wrs[k * CT + c], aR);
        }
        xl[(size_t)node * CT + c] = __float2half(aL);
        xr[(size_t)node * CT + c] = __float2half(aR);
    }
}

// ======= layer-2 node linear + residual: xl, xr, and res = b2 + hA @ Rw =======
template <int NPB>
__global__ __launch_bounds__(256) void nlh2_res_kernel(
    const __half* __restrict__ x,   // hA [N,32]
    const float* __restrict__ Wl, const float* __restrict__ bl,
    const float* __restrict__ Wr, const float* __restrict__ br,
    const float* __restrict__ Rw,   // [32,128] fp32
    const float* __restrict__ b2,   // [128]
    __half* __restrict__ xl, __half* __restrict__ xr,
    __half* __restrict__ res, int n) {
    constexpr int K = 32, CT = 128, K2 = K / 2;
    __shared__ h2 Wls[K2 * CT];
    __shared__ h2 Wrs[K2 * CT];
    __shared__ float Rws[K * CT];
    __shared__ h2 xs[NPB * K2];
    int tid = threadIdx.x;
    for (int i = tid; i < K2 * CT; i += 256) {
        int k2 = i / CT, c = i % CT;
        Wls[i] = h2{(_Float16)Wl[(2 * k2) * CT + c], (_Float16)Wl[(2 * k2 + 1) * CT + c]};
        Wrs[i] = h2{(_Float16)Wr[(2 * k2) * CT + c], (_Float16)Wr[(2 * k2 + 1) * CT + c]};
    }
    for (int i = tid; i < K * CT; i += 256) Rws[i] = Rw[i];
    int node0 = blockIdx.x * NPB;
    const unsigned* xg = (const unsigned*)(x + (size_t)node0 * K);
    for (int i = tid; i < NPB * K2; i += 256) {
        int nd = node0 + i / K2;
        unsigned u = (nd < n) ? xg[i] : 0u;
        xs[i] = bch2(u);
    }
    __syncthreads();
    int c = tid & 127, ty = tid >> 7;   // 2 node-slots
    int bound = (node0 + NPB < n) ? NPB : (n - node0);
    for (int local = ty; local < bound; local += 2) {
        int node = node0 + local;
        float aL = bl[c], aR = br[c], aS = b2[c];
        const h2* xrow = &xs[local * K2];
        for (int k = 0; k < K2; ++k) {
            h2 xv = xrow[k];
            aL = fdot2f(xv, Wls[k * CT + c], aL);
            aR = fdot2f(xv, Wrs[k * CT + c], aR);
            aS = fmaf((float)xv.x, Rws[(2 * k) * CT + c], aS);
            aS = fmaf((float)xv.y, Rws[(2 * k + 1) * CT + c], aS);
        }
        xl[(size_t)node * CT + c] = __float2half(aL);
        xr[(size_t)node * CT + c] = __float2half(aR);
        res[(size_t)node * CT + c] = __float2half(aS);
    }
}

// ================= CSR aggregation, CT=128 (layer 2) =================
// [validated 73.5us geometry] One wave per node; 2 edge-chains (32 lanes,
// 4 ch/lane); records 3 ahead; xl gather uses a 2-iteration-old src id.
// Now reads split ea/src arrays; gather offsets in 32-bit.
template <bool RELU, bool RES>
__global__ __launch_bounds__(256) void agg128_kernel(
    const int* __restrict__ rowptr,
    const uint4* __restrict__ ea_arr, const int* __restrict__ src_arr,
    const __half* __restrict__ xl, const __half* __restrict__ xr,
    const float* __restrict__ We,   // [8,128]
    const float* __restrict__ att,  // flat [128]
    const float* __restrict__ bias, // [128] (used only when !RES)
    __half* __restrict__ out, int n) {
    int tid = threadIdx.x;
    int node = (blockIdx.x * 256 + tid) >> 6;
    int lane = tid & 63;
    if (node >= n) return;
    int sub = lane >> 5, cl = lane & 31;
    int c0 = 4 * cl;
    h2 wch[4][4];
    float attc[4];
#pragma unroll
    for (int c = 0; c < 4; ++c) {
        attc[c] = att[c0 + c];
#pragma unroll
        for (int k = 0; k < 4; ++k)
            wch[c][k] = h2{(_Float16)We[(2 * k) * 128 + c0 + c],
                           (_Float16)We[(2 * k + 1) * 128 + c0 + c]};
    }
    int beg = rowptr[node], end = rowptr[node + 1];
    uint2 xru = *(const uint2*)&xr[(unsigned)(node * 128 + c0)];
    h2 xr01 = bch2(xru.x), xr23 = bch2(xru.y);
    float xrc[4] = {(float)xr01.x, (float)xr01.y, (float)xr23.x, (float)xr23.y};
    float num[4] = {0.f, 0.f, 0.f, 0.f};
    float den = 0.f;

    int j = beg + sub;
    // --- pipeline state: records at j, j+2, j+4 in flight; x for edge j ---
    uint4 u0, u1, u2; int s0, s1, s2; uint2 x0;
    if (j < end)     { u0 = ea_arr[j];     s0 = src_arr[j]; }
    if (j + 2 < end) { u1 = ea_arr[j + 2]; s1 = src_arr[j + 2]; }
    if (j + 4 < end) { u2 = ea_arr[j + 4]; s2 = src_arr[j + 4]; }
    if (j < end)     x0 = *(const uint2*)&xl[(unsigned)(s0 * 128 + c0)];
    while (j < end) {
        uint4 uT; int sT; uint2 xT;
        if (j + 6 < end) { uT = ea_arr[j + 6]; sT = src_arr[j + 6]; }
        if (j + 2 < end) { xT = *(const uint2*)&xl[(unsigned)(s1 * 128 + c0)]; } // s1: 2 iters old
        h2 e0 = bch2(u0.x), e1 = bch2(u0.y), e2 = bch2(u0.z), e3 = bch2(u0.w);
        h2 xl01 = bch2(x0.x), xl23 = bch2(x0.y);
        float xls[4] = {(float)xl01.x, (float)xl01.y, (float)xl23.x, (float)xl23.y};
        float p = 0.f;
#pragma unroll
        for (int c = 0; c < 4; ++c) {
            float m = xls[c] + xrc[c];
            m = fdot2f(e0, wch[c][0], m); m = fdot2f(e1, wch[c][1], m);
            m = fdot2f(e2, wch[c][2], m); m = fdot2f(e3, wch[c][3], m);
            float sv = fmaxf(m, 0.f) + NEG_SLOPE * fminf(m, 0.f);
            p = fmaf(sv, attc[c], p);
        }
        p += __shfl_xor(p, 1); p += __shfl_xor(p, 2); p += __shfl_xor(p, 4); // 8-lane head
        float wgt = __expf(p);
#pragma unroll
        for (int c = 0; c < 4; ++c) num[c] = fmaf(wgt, xls[c], num[c]);
        den += wgt;
        j += 2;
        u0 = u1; u1 = u2; u2 = uT;
        s1 = s2; s2 = sT;
        x0 = xT;
    }
    // combine the two 32-lane chains
#pragma unroll
    for (int c = 0; c < 4; ++c) num[c] += __shfl_xor(num[c], 32);
    den += __shfl_xor(den, 32);
    if (sub == 0) {
        float inv = 1.f / den;
        float base[4];
        if (RES) {
            uint2 ru = *(const uint2*)&out[(unsigned)(node * 128 + c0)];
            h2 r01 = bch2(ru.x), r23 = bch2(ru.y);
            base[0] = (float)r01.x; base[1] = (float)r01.y;
            base[2] = (float)r23.x; base[3] = (float)r23.y;
        } else {
#pragma unroll
            for (int c = 0; c < 4; ++c) base[c] = bias[c0 + c];
        }
        float v[4];
#pragma unroll
        for (int c = 0; c < 4; ++c) v[c] = fmaf(num[c], inv, base[c]);
        if (RELU) {
#pragma unroll
            for (int c = 0; c < 4; ++c) v[c] = fmaxf(v[c], 0.f);
        }
        __half2 o01 = __floats2half2_rn(v[0], v[1]);
        __half2 o23 = __floats2half2_rn(v[2], v[3]);
        uint2 ou; ou.x = *(unsigned*)&o01; ou.y = *(unsigned*)&o23;
        *(uint2*)&out[(unsigned)(node * 128 + c0)] = ou;
    }
}

// ================= CSR aggregation, CT=32 (layers 1, 3) =================
// [validated R11 geometry] 2 chains x 16 lanes per node; records 3 ahead;
// xl gather uses a 2-iteration-old src id. Split ea/src arrays.
template <int HC, bool RELU, typename OUT>
__global__ __launch_bounds__(256) void agg32_kernel(
    const int* __restrict__ rowptr,
    const uint4* __restrict__ ea_arr, const int* __restrict__ src_arr,
    const __half* __restrict__ xl, const __half* __restrict__ xr,
    const float* __restrict__ We,   // [8,32]
    const float* __restrict__ att,  // flat [32]
    const float* __restrict__ bias, // [32]
    OUT* __restrict__ out, int n) {
    int tid = threadIdx.x;
    int node = (blockIdx.x * 256 + tid) >> 5;   // 32 lanes per node
    int lane = tid & 31;
    if (node >= n) return;
    int sub = lane >> 4, q = lane & 15;         // chain id, lane-in-chain
    int c0 = 2 * q;
    h2 wc0[4], wc1[4];
#pragma unroll
    for (int k = 0; k < 4; ++k) {
        wc0[k] = h2{(_Float16)We[(2 * k) * 32 + c0], (_Float16)We[(2 * k + 1) * 32 + c0]};
        wc1[k] = h2{(_Float16)We[(2 * k) * 32 + c0 + 1], (_Float16)We[(2 * k + 1) * 32 + c0 + 1]};
    }
    float att0 = att[c0], att1 = att[c0 + 1];
    int beg = rowptr[node], end = rowptr[node + 1];
    h2 xrh = bch2(*(const unsigned*)&xr[(unsigned)(node * 32 + c0)]);
    float xrc0 = (float)xrh.x, xrc1 = (float)xrh.y;
    float num0 = 0.f, num1 = 0.f, den = 0.f;

    int j = beg + sub;
    uint4 u0, u1, u2; int s0, s1, s2; unsigned x0;
    if (j < end)     { u0 = ea_arr[j];     s0 = src_arr[j]; }
    if (j + 2 < end) { u1 = ea_arr[j + 2]; s1 = src_arr[j + 2]; }
    if (j + 4 < end) { u2 = ea_arr[j + 4]; s2 = src_arr[j + 4]; }
    if (j < end)     x0 = *(const unsigned*)&xl[(unsigned)(s0 * 32 + c0)];
    while (j < end) {
        uint4 uT; int sT; unsigned xT;
        if (j + 6 < end) { uT = ea_arr[j + 6]; sT = src_arr[j + 6]; }
        if (j + 2 < end) { xT = *(const unsigned*)&xl[(unsigned)(s1 * 32 + c0)]; } // s1: 2 iters old
        h2 e0 = bch2(u0.x), e1 = bch2(u0.y), e2 = bch2(u0.z), e3 = bch2(u0.w);
        h2 xlh = bch2(x0);
        float xls0 = (float)xlh.x, xls1 = (float)xlh.y;
        float m0 = xls0 + xrc0, m1 = xls1 + xrc1;
        m0 = fdot2f(e0, wc0[0], m0); m0 = fdot2f(e1, wc0[1], m0);
        m0 = fdot2f(e2, wc0[2], m0); m0 = fdot2f(e3, wc0[3], m0);
        m1 = fdot2f(e0, wc1[0], m1); m1 = fdot2f(e1, wc1[1], m1);
        m1 = fdot2f(e2, wc1[2], m1); m1 = fdot2f(e3, wc1[3], m1);
        float s0v = fmaxf(m0, 0.f) + NEG_SLOPE * fminf(m0, 0.f);
        float s1v = fmaxf(m1, 0.f) + NEG_SLOPE * fminf(m1, 0.f);
        float p = fmaf(s0v, att0, s1v * att1);
#pragma unroll
        for (int off = HC / 4; off > 0; off >>= 1) p += __shfl_xor(p, off); // head (<=16 lanes)
        float wgt = __expf(p);
        num0 = fmaf(wgt, xls0, num0);
        num1 = fmaf(wgt, xls1, num1);
        den += wgt;
        j += 2;
        u0 = u1; u1 = u2; u2 = uT;
        s1 = s2; s2 = sT;
        x0 = xT;
    }
    // combine the two 16-lane chains
    num0 += __shfl_xor(num0, 16);
    num1 += __shfl_xor(num1, 16);
    den  += __shfl_xor(den, 16);
    if (sub == 0) {
        float inv = 1.f / den;
        float v0 = num0 * inv + bias[c0];
        float v1 = num1 * inv + bias[c0 + 1];
        if (RELU) { v0 = fmaxf(v0, 0.f); v1 = fmaxf(v1, 0.f); }
        if constexpr (sizeof(OUT) == 2) {
            __half2 o = __floats2half2_rn(v0, v1);
            *(__half2*)&out[(unsigned)(node * 32 + c0)] = o;
        } else {
            float2 o; o.x = v0; o.y = v1;
            *(float2*)&out[(size_t)node * 32 + c0] = o;
        }
    }
}

extern "C" void kernel_launch(void* const* d_in, const int* in_sizes, int n_in,
                              void* d_out, int out_size, void* d_ws, size_t ws_size,
                              hipStream_t stream) {
    const float* x    = (const float*)d_in[0];
    const int* ei     = (const int*)d_in[1];
    const float* eatt = (const float*)d_in[2];
    const float* Wl1 = (const float*)d_in[3],  *bl1 = (const float*)d_in[4];
    const float* Wr1 = (const float*)d_in[5],  *br1 = (const float*)d_in[6];
    const float* We1 = (const float*)d_in[7],  *att1 = (const float*)d_in[8];
    const float* b1  = (const float*)d_in[9];
    const float* Wl2 = (const float*)d_in[10], *bl2 = (const float*)d_in[11];
    const float* Wr2 = (const float*)d_in[12], *br2 = (const float*)d_in[13];
    const float* We2 = (const float*)d_in[14], *att2 = (const float*)d_in[15];
    const float* b2  = (const float*)d_in[16], *Rw2 = (const float*)d_in[17];
    const float* Wl3 = (const float*)d_in[18], *bl3 = (const float*)d_in[19];
    const float* Wr3 = (const float*)d_in[20], *br3 = (const float*)d_in[21];
    const float* We3 = (const float*)d_in[22], *att3 = (const float*)d_in[23];
    const float* b3  = (const float*)d_in[24];

    const int* srcp = ei;
    const int* dstp = ei + EE;

    // ---- workspace layout (~50 MB) ----
    char* w = (char*)d_ws;
    size_t off = 0;
    auto alloc = [&](size_t bytes) { char* p = w + off; off += (bytes + 255) & ~size_t(255); return p; };
    int*    rowcnt   = (int*)alloc((size_t)NN * 4);
    int*    rowptr   = (int*)alloc((size_t)(NN + 1) * 4);
    int*    cursor   = (int*)alloc((size_t)NN * 4);
    int*    blocksum = (int*)alloc(256 * 4);
    uint4*  ea_arr   = (uint4*)alloc((size_t)(EE + NN) * 16);
    int*    src_arr  = (int*)alloc((size_t)(EE + NN) * 4);
    __half* xlbuf    = (__half*)alloc((size_t)NN * 128 * 2);
    __half* xrbuf    = (__half*)alloc((size_t)NN * 128 * 2);
    __half* hA       = (__half*)alloc((size_t)NN * 32 * 2);
    __half* hB       = (__half*)alloc((size_t)NN * 128 * 2);

    int nb = cdiv(NN, 256);

    // ---- CSR build (self-loop in front slot of each row) ----
    hipMemsetAsync(rowcnt, 0, (size_t)NN * 4, stream);
    hist_kernel<<<cdiv(EE / 4, 256), 256, 0, stream>>>((const int4*)dstp, rowcnt, EE / 4);
    scana_kernel<<<nb, 256, 0, stream>>>(rowcnt, blocksum, NN);
    scanb_kernel<<<nb, 256, 0, stream>>>(rowcnt, blocksum, nb, rowptr, cursor, src_arr, NN);
    scatter_kernel<<<cdiv(EE, 256), 256, 0, stream>>>(
        srcp, dstp, eatt, cursor, ea_arr, src_arr, EE);

    // ---- fused: loop_sea + node_linear layer 1 ----
    constexpr int NB1 = (NN + 7) / 8;
    int nb_ls = cdiv(NN, 4);
    fused_nl1_loopsea_kernel<NB1><<<NB1 + nb_ls, 256, 0, stream>>>(
        x, Wl1, bl1, Wr1, br1, xlbuf, xrbuf, rowptr, ea_arr, NN);

    // ---- layer 1 aggregation: H=4, C=8 (CT=32, 2 chains/node) ----
    agg32_kernel<8, true, __half><<<cdiv(NN, 8), 256, 0, stream>>>(
        rowptr, ea_arr, src_arr, xlbuf, xrbuf, We1, att1, b1, hA, NN);

    // ---- layer 2: IN=32 -> H=4, C=32 (CT=128), residual fused into nlh2 ----
    nlh2_res_kernel<32><<<cdiv(NN, 32), 256, 0, stream>>>(
        hA, Wl2, bl2, Wr2, br2, Rw2, b2, xlbuf, xrbuf, hB, NN);
    agg128_kernel<true, true><<<cdiv(NN, 4), 256, 0, stream>>>(
        rowptr, ea_arr, src_arr, xlbuf, xrbuf, We2, att2, b2, hB, NN);

    // ---- layer 3: IN=128 -> H=1, C=32 (CT=32, 2 chains/node) ----
    node_linear_h_kernel<128, 32, 64><<<cdiv(NN, 64), 256, 0, stream>>>(
        hB, Wl3, bl3, Wr3, br3, xlbuf, xrbuf, NN);
    agg32_kernel<32, false, float><<<cdiv(NN, 8), 256, 0, stream>>>(
        rowptr, ea_arr, src_arr, xlbuf, xrbuf, We3, att3, b3,
        (float*)d_out, NN);
}

// Round 13
// 402.033 us; speedup vs baseline: 1.0071x; 1.0071x over previous
//
#include <hip/hip_runtime.h>
#include <hip/hip_fp16.h>

#define NEG_SLOPE 0.2f

constexpr int NN = 50000;   // nodes
constexpr int EE = 800000;  // edges (before self loops)

static inline int cdiv(int a, int b) { return (a + b - 1) / b; }

typedef _Float16 h2 __attribute__((ext_vector_type(2)));

#if __has_builtin(__builtin_amdgcn_fdot2)
static __device__ inline float fdot2f(h2 a, h2 b, float c) {
    return __builtin_amdgcn_fdot2(a, b, c, false);
}
#else
static __device__ inline float fdot2f(h2 a, h2 b, float c) {
    return c + (float)a.x * (float)b.x + (float)a.y * (float)b.y;
}
#endif

static __device__ inline h2 bch2(unsigned u) { return __builtin_bit_cast(h2, u); }

// Edge data: split arrays.
//   ea_arr[slot]  : uint4 = 8 fp16 edge attrs (16B, aligned)
//   src_arr[slot] : int   = source node id
// Self-loop slot (row front) ea is written by agg32<SELF> (fused loop_sea).

// ================= CSR build =================
__global__ void hist_kernel(const int4* __restrict__ dst4, int* __restrict__ rowcnt, int E4) {
    int t = blockIdx.x * blockDim.x + threadIdx.x;
    if (t >= E4) return;
    int4 d = dst4[t];
    atomicAdd(&rowcnt[d.x], 1);
    atomicAdd(&rowcnt[d.y], 1);
    atomicAdd(&rowcnt[d.z], 1);
    atomicAdd(&rowcnt[d.w], 1);
}

__global__ void scana_kernel(const int* __restrict__ cnt, int* __restrict__ blocksum, int n) {
    __shared__ int s[256];
    int t = threadIdx.x, g = blockIdx.x * 256 + t;
    s[t] = (g < n) ? cnt[g] + 1 : 0;
    __syncthreads();
    for (int off = 128; off > 0; off >>= 1) {
        if (t < off) s[t] += s[t + off];
        __syncthreads();
    }
    if (t == 0) blocksum[blockIdx.x] = s[0];
}

__global__ void scanb_kernel(const int* __restrict__ cnt, const int* __restrict__ blocksum,
                             int nbk, int* __restrict__ rowptr, int* __restrict__ cursor,
                             int* __restrict__ src_arr, int n) {
    __shared__ int bs[256];
    __shared__ int s[256];
    int t = threadIdx.x;
    bs[t] = (t < nbk) ? blocksum[t] : 0;
    __syncthreads();
    for (int off = 1; off < 256; off <<= 1) {
        int tv = (t >= off) ? bs[t - off] : 0; __syncthreads();
        bs[t] += tv; __syncthreads();
    }
    int blockoff = (blockIdx.x > 0) ? bs[blockIdx.x - 1] : 0;
    int g = blockIdx.x * 256 + t;
    int val = (g < n) ? cnt[g] + 1 : 0;
    s[t] = val; __syncthreads();
    for (int off = 1; off < 256; off <<= 1) {
        int tv = (t >= off) ? s[t - off] : 0; __syncthreads();
        s[t] += tv; __syncthreads();
    }
    if (g >= n) return;
    int incl = s[t] + blockoff;
    rowptr[g + 1] = incl;
    int beg = incl - val;
    cursor[g] = beg + 1;          // slot `beg` reserved for the self loop
    src_arr[beg] = g;             // self-loop source
    if (g == 0) rowptr[0] = 0;
}

__global__ void scatter_kernel(const int* __restrict__ src, const int* __restrict__ dst,
                               const float* __restrict__ eattr,
                               int* __restrict__ cursor,
                               uint4* __restrict__ ea_arr, int* __restrict__ src_arr, int E) {
    int t = blockIdx.x * blockDim.x + threadIdx.x;
    if (t >= E) return;
    int d = dst[t];
    int pos = atomicAdd(&cursor[d], 1);
    const float4* ea4 = (const float4*)(eattr + (size_t)t * 8);
    float4 a = ea4[0], b = ea4[1];
    __half2 h0 = __floats2half2_rn(a.x, a.y);
    __half2 h1 = __floats2half2_rn(a.z, a.w);
    __half2 h2v = __floats2half2_rn(b.x, b.y);
    __half2 h3 = __floats2half2_rn(b.z, b.w);
    uint4 u;
    u.x = *(unsigned*)&h0; u.y = *(unsigned*)&h1;
    u.z = *(unsigned*)&h2v; u.w = *(unsigned*)&h3;
    ea_arr[pos] = u;
    src_arr[pos] = src[t];
}

// ======= node_linear layer-1 (loop_sea now fused into agg32<SELF>) =========
__global__ __launch_bounds__(256) void nl1_kernel(
    const float* __restrict__ x,
    const float* __restrict__ Wl, const float* __restrict__ bl,
    const float* __restrict__ Wr, const float* __restrict__ br,
    __half* __restrict__ xl, __half* __restrict__ xr, int n) {
    constexpr int K = 16, CT = 32, NPB = 8;
    __shared__ float Wls[K * CT];
    __shared__ float Wrs[K * CT];
    __shared__ float xs[NPB * K];
    int tid = threadIdx.x;
    int ty = tid >> 5, c = tid & 31;
    for (int i = tid; i < K * CT; i += 256) { Wls[i] = Wl[i]; Wrs[i] = Wr[i]; }
    int node0 = blockIdx.x * NPB;
    for (int i = tid; i < NPB * K; i += 256) {
        int nd = node0 + i / K;
        xs[i] = (nd < n) ? x[(size_t)node0 * K + i] : 0.f;
    }
    __syncthreads();
    int node = node0 + ty;
    if (node >= n) return;
    float aL = bl[c], aR = br[c];
    const float* xrow = &xs[ty * K];
    for (int k = 0; k < K; ++k) {
        float xv = xrow[k];
        aL = fmaf(xv, Wls[k * CT + c], aL);
        aR = fmaf(xv, Wrs[k * CT + c], aR);
    }
    xl[(size_t)node * CT + c] = __float2half(aL);
    xr[(size_t)node * CT + c] = __float2half(aR);
}

// ======= node linear (fp16 input, fp16 LDS weights, fdot2, node-loop) ========
template <int K, int CT, int NPB>
__global__ __launch_bounds__(256) void node_linear_h_kernel(
    const __half* __restrict__ x,
    const float* __restrict__ Wl, const float* __restrict__ bl,
    const float* __restrict__ Wr, const float* __restrict__ br,
    __half* __restrict__ xl, __half* __restrict__ xr, int n) {
    constexpr int K2 = K / 2;
    constexpr int TS = 256 / CT;     // node-slots per pass
    __shared__ h2 Wls[K2 * CT];
    __shared__ h2 Wrs[K2 * CT];
    __shared__ h2 xs[NPB * K2];
    int tid = threadIdx.x;
    for (int i = tid; i < K2 * CT; i += 256) {
        int k2 = i / CT, c = i % CT;
        Wls[i] = h2{(_Float16)Wl[(2 * k2) * CT + c], (_Float16)Wl[(2 * k2 + 1) * CT + c]};
        Wrs[i] = h2{(_Float16)Wr[(2 * k2) * CT + c], (_Float16)Wr[(2 * k2 + 1) * CT + c]};
    }
    int node0 = blockIdx.x * NPB;
    const unsigned* xg = (const unsigned*)(x + (size_t)node0 * K);
    for (int i = tid; i < NPB * K2; i += 256) {
        int nd = node0 + i / K2;
        unsigned u = (nd < n) ? xg[i] : 0u;
        xs[i] = bch2(u);
    }
    __syncthreads();
    int c = tid % CT, ty = tid / CT;
    int bound = (node0 + NPB < n) ? NPB : (n - node0);
    for (int local = ty; local < bound; local += TS) {
        int node = node0 + local;
        float aL = bl[c], aR = br[c];
        const h2* xrow = &xs[local * K2];
        for (int k = 0; k < K2; ++k) {
            h2 xv = xrow[k];
            aL = fdot2f(xv, Wls[k * CT + c], aL);
            aR = fdot2f(xv, Wrs[k * CT + c], aR);
        }
        xl[(size_t)node * CT + c] = __float2half(aL);
        xr[(size_t)node * CT + c] = __float2half(aR);
    }
}

// ======= layer-2 node linear + residual: xl, xr, and res = b2 + hA @ Rw =======
template <int NPB>
__global__ __launch_bounds__(256) void nlh2_res_kernel(
    const __half* __restrict__ x,   // hA [N,32]
    const float* __restrict__ Wl, const float* __restrict__ bl,
    const float* __restrict__ Wr, const float* __restrict__ br,
    const float* __restrict__ Rw,   // [32,128] fp32
    const float* __restrict__ b2,   // [128]
    __half* __restrict__ xl, __half* __restrict__ xr,
    __half* __restrict__ res, int n) {
    constexpr int K = 32, CT = 128, K2 = K / 2;
    __shared__ h2 Wls[K2 * CT];
    __shared__ h2 Wrs[K2 * CT];
    __shared__ float Rws[K * CT];
    __shared__ h2 xs[NPB * K2];
    int tid = threadIdx.x;
    for (int i = tid; i < K2 * CT; i += 256) {
        int k2 = i / CT, c = i % CT;
        Wls[i] = h2{(_Float16)Wl[(2 * k2) * CT + c], (_Float16)Wl[(2 * k2 + 1) * CT + c]};
        Wrs[i] = h2{(_Float16)Wr[(2 * k2) * CT + c], (_Float16)Wr[(2 * k2 + 1) * CT + c]};
    }
    for (int i = tid; i < K * CT; i += 256) Rws[i] = Rw[i];
    int node0 = blockIdx.x * NPB;
    const unsigned* xg = (const unsigned*)(x + (size_t)node0 * K);
    for (int i = tid; i < NPB * K2; i += 256) {
        int nd = node0 + i / K2;
        unsigned u = (nd < n) ? xg[i] : 0u;
        xs[i] = bch2(u);
    }
    __syncthreads();
    int c = tid & 127, ty = tid >> 7;   // 2 node-slots
    int bound = (node0 + NPB < n) ? NPB : (n - node0);
    for (int local = ty; local < bound; local += 2) {
        int node = node0 + local;
        float aL = bl[c], aR = br[c], aS = b2[c];
        const h2* xrow = &xs[local * K2];
        for (int k = 0; k < K2; ++k) {
            h2 xv = xrow[k];
            aL = fdot2f(xv, Wls[k * CT + c], aL);
            aR = fdot2f(xv, Wrs[k * CT + c], aR);
            aS = fmaf((float)xv.x, Rws[(2 * k) * CT + c], aS);
            aS = fmaf((float)xv.y, Rws[(2 * k + 1) * CT + c], aS);
        }
        xl[(size_t)node * CT + c] = __float2half(aL);
        xr[(size_t)node * CT + c] = __float2half(aR);
        res[(size_t)node * CT + c] = __float2half(aS);
    }
}

// ================= CSR aggregation, CT=128 (layer 2) =================
// [validated geometry] One wave per node; 2 edge-chains (32 lanes, 4 ch/lane);
// records 3 ahead; xl gather uses a 2-iteration-old src id.
template <bool RELU, bool RES>
__global__ __launch_bounds__(256) void agg128_kernel(
    const int* __restrict__ rowptr,
    const uint4* __restrict__ ea_arr, const int* __restrict__ src_arr,
    const __half* __restrict__ xl, const __half* __restrict__ xr,
    const float* __restrict__ We,   // [8,128]
    const float* __restrict__ att,  // flat [128]
    const float* __restrict__ bias, // [128] (used only when !RES)
    __half* __restrict__ out, int n) {
    int tid = threadIdx.x;
    int node = (blockIdx.x * 256 + tid) >> 6;
    int lane = tid & 63;
    if (node >= n) return;
    int sub = lane >> 5, cl = lane & 31;
    int c0 = 4 * cl;
    h2 wch[4][4];
    float attc[4];
#pragma unroll
    for (int c = 0; c < 4; ++c) {
        attc[c] = att[c0 + c];
#pragma unroll
        for (int k = 0; k < 4; ++k)
            wch[c][k] = h2{(_Float16)We[(2 * k) * 128 + c0 + c],
                           (_Float16)We[(2 * k + 1) * 128 + c0 + c]};
    }
    int beg = rowptr[node], end = rowptr[node + 1];
    uint2 xru = *(const uint2*)&xr[(unsigned)(node * 128 + c0)];
    h2 xr01 = bch2(xru.x), xr23 = bch2(xru.y);
    float xrc[4] = {(float)xr01.x, (float)xr01.y, (float)xr23.x, (float)xr23.y};
    float num[4] = {0.f, 0.f, 0.f, 0.f};
    float den = 0.f;

    int j = beg + sub;
    uint4 u0, u1, u2; int s0, s1, s2; uint2 x0;
    if (j < end)     { u0 = ea_arr[j];     s0 = src_arr[j]; }
    if (j + 2 < end) { u1 = ea_arr[j + 2]; s1 = src_arr[j + 2]; }
    if (j + 4 < end) { u2 = ea_arr[j + 4]; s2 = src_arr[j + 4]; }
    if (j < end)     x0 = *(const uint2*)&xl[(unsigned)(s0 * 128 + c0)];
    while (j < end) {
        uint4 uT; int sT; uint2 xT;
        if (j + 6 < end) { uT = ea_arr[j + 6]; sT = src_arr[j + 6]; }
        if (j + 2 < end) { xT = *(const uint2*)&xl[(unsigned)(s1 * 128 + c0)]; } // s1: 2 iters old
        h2 e0 = bch2(u0.x), e1 = bch2(u0.y), e2 = bch2(u0.z), e3 = bch2(u0.w);
        h2 xl01 = bch2(x0.x), xl23 = bch2(x0.y);
        float xls[4] = {(float)xl01.x, (float)xl01.y, (float)xl23.x, (float)xl23.y};
        float p = 0.f;
#pragma unroll
        for (int c = 0; c < 4; ++c) {
            float m = xls[c] + xrc[c];
            m = fdot2f(e0, wch[c][0], m); m = fdot2f(e1, wch[c][1], m);
            m = fdot2f(e2, wch[c][2], m); m = fdot2f(e3, wch[c][3], m);
            float sv = fmaxf(m, 0.f) + NEG_SLOPE * fminf(m, 0.f);
            p = fmaf(sv, attc[c], p);
        }
        p += __shfl_xor(p, 1); p += __shfl_xor(p, 2); p += __shfl_xor(p, 4); // 8-lane head
        float wgt = __expf(p);
#pragma unroll
        for (int c = 0; c < 4; ++c) num[c] = fmaf(wgt, xls[c], num[c]);
        den += wgt;
        j += 2;
        u0 = u1; u1 = u2; u2 = uT;
        s1 = s2; s2 = sT;
        x0 = xT;
    }
#pragma unroll
    for (int c = 0; c < 4; ++c) num[c] += __shfl_xor(num[c], 32);
    den += __shfl_xor(den, 32);
    if (sub == 0) {
        float inv = 1.f / den;
        float base[4];
        if (RES) {
            uint2 ru = *(const uint2*)&out[(unsigned)(node * 128 + c0)];
            h2 r01 = bch2(ru.x), r23 = bch2(ru.y);
            base[0] = (float)r01.x; base[1] = (float)r01.y;
            base[2] = (float)r23.x; base[3] = (float)r23.y;
        } else {
#pragma unroll
            for (int c = 0; c < 4; ++c) base[c] = bias[c0 + c];
        }
        float v[4];
#pragma unroll
        for (int c = 0; c < 4; ++c) v[c] = fmaf(num[c], inv, base[c]);
        if (RELU) {
#pragma unroll
            for (int c = 0; c < 4; ++c) v[c] = fmaxf(v[c], 0.f);
        }
        __half2 o01 = __floats2half2_rn(v[0], v[1]);
        __half2 o23 = __floats2half2_rn(v[2], v[3]);
        uint2 ou; ou.x = *(unsigned*)&o01; ou.y = *(unsigned*)&o23;
        *(uint2*)&out[(unsigned)(node * 128 + c0)] = ou;
    }
}

// ================= CSR aggregation, CT=32 (layers 1, 3) =================
// 2 chains x 16 lanes per node; records 3 ahead; xl gather uses a
// 2-iteration-old src id.
// SELF=true (layer 1): loop_sea fused — non-self edges accumulate fp32
// channel sums of ea; after the loop the fp16 mean is written to
// ea_arr[beg] (read later by layers 2/3) and the self-loop edge is
// processed through the same per-edge math with ea = mean.
// Numerics bit-identical to the separate loop_sea pass (fp32 sum of fp16
// values, rn-rounded fp16 mean).
template <int HC, bool SELF, bool RELU, typename OUT>
__global__ __launch_bounds__(256) void agg32_kernel(
    const int* __restrict__ rowptr,
    uint4* __restrict__ ea_arr, const int* __restrict__ src_arr,
    const __half* __restrict__ xl, const __half* __restrict__ xr,
    const float* __restrict__ We,   // [8,32]
    const float* __restrict__ att,  // flat [32]
    const float* __restrict__ bias, // [32]
    OUT* __restrict__ out, int n) {
    int tid = threadIdx.x;
    int node = (blockIdx.x * 256 + tid) >> 5;   // 32 lanes per node
    int lane = tid & 31;
    if (node >= n) return;
    int sub = lane >> 4, q = lane & 15;         // chain id, lane-in-chain
    int c0 = 2 * q;
    h2 wc0[4], wc1[4];
#pragma unroll
    for (int k = 0; k < 4; ++k) {
        wc0[k] = h2{(_Float16)We[(2 * k) * 32 + c0], (_Float16)We[(2 * k + 1) * 32 + c0]};
        wc1[k] = h2{(_Float16)We[(2 * k) * 32 + c0 + 1], (_Float16)We[(2 * k + 1) * 32 + c0 + 1]};
    }
    float att0 = att[c0], att1 = att[c0 + 1];
    int beg = rowptr[node], end = rowptr[node + 1];
    h2 xrh = bch2(*(const unsigned*)&xr[(unsigned)(node * 32 + c0)]);
    float xrc0 = (float)xrh.x, xrc1 = (float)xrh.y;
    float num0 = 0.f, num1 = 0.f, den = 0.f;
    float easum[8] = {0.f, 0.f, 0.f, 0.f, 0.f, 0.f, 0.f, 0.f};  // SELF only

    int j = beg + (SELF ? 1 : 0) + sub;   // SELF: skip the (unwritten) self slot
    uint4 u0, u1, u2; int s0, s1, s2; unsigned x0;
    if (j < end)     { u0 = ea_arr[j];     s0 = src_arr[j]; }
    if (j + 2 < end) { u1 = ea_arr[j + 2]; s1 = src_arr[j + 2]; }
    if (j + 4 < end) { u2 = ea_arr[j + 4]; s2 = src_arr[j + 4]; }
    if (j < end)     x0 = *(const unsigned*)&xl[(unsigned)(s0 * 32 + c0)];
    while (j < end) {
        uint4 uT; int sT; unsigned xT;
        if (j + 6 < end) { uT = ea_arr[j + 6]; sT = src_arr[j + 6]; }
        if (j + 2 < end) { xT = *(const unsigned*)&xl[(unsigned)(s1 * 32 + c0)]; } // s1: 2 iters old
        h2 e0 = bch2(u0.x), e1 = bch2(u0.y), e2 = bch2(u0.z), e3 = bch2(u0.w);
        if (SELF) {
            easum[0] += (float)e0.x; easum[1] += (float)e0.y;
            easum[2] += (float)e1.x; easum[3] += (float)e1.y;
            easum[4] += (float)e2.x; easum[5] += (float)e2.y;
            easum[6] += (float)e3.x; easum[7] += (float)e3.y;
        }
        h2 xlh = bch2(x0);
        float xls0 = (float)xlh.x, xls1 = (float)xlh.y;
        float m0 = xls0 + xrc0, m1 = xls1 + xrc1;
        m0 = fdot2f(e0, wc0[0], m0); m0 = fdot2f(e1, wc0[1], m0);
        m0 = fdot2f(e2, wc0[2], m0); m0 = fdot2f(e3, wc0[3], m0);
        m1 = fdot2f(e0, wc1[0], m1); m1 = fdot2f(e1, wc1[1], m1);
        m1 = fdot2f(e2, wc1[2], m1); m1 = fdot2f(e3, wc1[3], m1);
        float s0v = fmaxf(m0, 0.f) + NEG_SLOPE * fminf(m0, 0.f);
        float s1v = fmaxf(m1, 0.f) + NEG_SLOPE * fminf(m1, 0.f);
        float p = fmaf(s0v, att0, s1v * att1);
#pragma unroll
        for (int off = HC / 4; off > 0; off >>= 1) p += __shfl_xor(p, off); // head (<=16 lanes)
        float wgt = __expf(p);
        num0 = fmaf(wgt, xls0, num0);
        num1 = fmaf(wgt, xls1, num1);
        den += wgt;
        j += 2;
        u0 = u1; u1 = u2; u2 = uT;
        s1 = s2; s2 = sT;
        x0 = xT;
    }
    if (SELF) {
        // combine chain sums (each lane of a chain holds identical full sums)
#pragma unroll
        for (int c = 0; c < 8; ++c) easum[c] += __shfl_xor(easum[c], 16);
        float invc = 1.f / fmaxf((float)(end - beg - 1), 1.f);
        h2 mh0 = h2{(_Float16)(easum[0] * invc), (_Float16)(easum[1] * invc)};
        h2 mh1 = h2{(_Float16)(easum[2] * invc), (_Float16)(easum[3] * invc)};
        h2 mh2 = h2{(_Float16)(easum[4] * invc), (_Float16)(easum[5] * invc)};
        h2 mh3 = h2{(_Float16)(easum[6] * invc), (_Float16)(easum[7] * invc)};
        if (lane == 0) {
            uint4 mu;
            mu.x = __builtin_bit_cast(unsigned, mh0);
            mu.y = __builtin_bit_cast(unsigned, mh1);
            mu.z = __builtin_bit_cast(unsigned, mh2);
            mu.w = __builtin_bit_cast(unsigned, mh3);
            ea_arr[beg] = mu;                    // for layers 2/3
        }
        // self-loop edge: ea = mean, src = node (computed on all lanes,
        // accumulated on chain 0 only)
        h2 xlh = bch2(*(const unsigned*)&xl[(unsigned)(node * 32 + c0)]);
        float xls0 = (float)xlh.x, xls1 = (float)xlh.y;
        float m0 = xls0 + xrc0, m1 = xls1 + xrc1;
        m0 = fdot2f(mh0, wc0[0], m0); m0 = fdot2f(mh1, wc0[1], m0);
        m0 = fdot2f(mh2, wc0[2], m0); m0 = fdot2f(mh3, wc0[3], m0);
        m1 = fdot2f(mh0, wc1[0], m1); m1 = fdot2f(mh1, wc1[1], m1);
        m1 = fdot2f(mh2, wc1[2], m1); m1 = fdot2f(mh3, wc1[3], m1);
        float s0v = fmaxf(m0, 0.f) + NEG_SLOPE * fminf(m0, 0.f);
        float s1v = fmaxf(m1, 0.f) + NEG_SLOPE * fminf(m1, 0.f);
        float p = fmaf(s0v, att0, s1v * att1);
#pragma unroll
        for (int off = HC / 4; off > 0; off >>= 1) p += __shfl_xor(p, off);
        float wgt = __expf(p);
        if (sub == 0) {
            num0 = fmaf(wgt, xls0, num0);
            num1 = fmaf(wgt, xls1, num1);
            den += wgt;
        }
    }
    // combine the two 16-lane chains
    num0 += __shfl_xor(num0, 16);
    num1 += __shfl_xor(num1, 16);
    den  += __shfl_xor(den, 16);
    if (sub == 0) {
        float inv = 1.f / den;
        float v0 = num0 * inv + bias[c0];
        float v1 = num1 * inv + bias[c0 + 1];
        if (RELU) { v0 = fmaxf(v0, 0.f); v1 = fmaxf(v1, 0.f); }
        if constexpr (sizeof(OUT) == 2) {
            __half2 o = __floats2half2_rn(v0, v1);
            *(__half2*)&out[(unsigned)(node * 32 + c0)] = o;
        } else {
            float2 o; o.x = v0; o.y = v1;
            *(float2*)&out[(size_t)node * 32 + c0] = o;
        }
    }
}

extern "C" void kernel_launch(void* const* d_in, const int* in_sizes, int n_in,
                              void* d_out, int out_size, void* d_ws, size_t ws_size,
                              hipStream_t stream) {
    const float* x    = (const float*)d_in[0];
    const int* ei     = (const int*)d_in[1];
    const float* eatt = (const float*)d_in[2];
    const float* Wl1 = (const float*)d_in[3],  *bl1 = (const float*)d_in[4];
    const float* Wr1 = (const float*)d_in[5],  *br1 = (const float*)d_in[6];
    const float* We1 = (const float*)d_in[7],  *att1 = (const float*)d_in[8];
    const float* b1  = (const float*)d_in[9];
    const float* Wl2 = (const float*)d_in[10], *bl2 = (const float*)d_in[11];
    const float* Wr2 = (const float*)d_in[12], *br2 = (const float*)d_in[13];
    const float* We2 = (const float*)d_in[14], *att2 = (const float*)d_in[15];
    const float* b2  = (const float*)d_in[16], *Rw2 = (const float*)d_in[17];
    const float* Wl3 = (const float*)d_in[18], *bl3 = (const float*)d_in[19];
    const float* Wr3 = (const float*)d_in[20], *br3 = (const float*)d_in[21];
    const float* We3 = (const float*)d_in[22], *att3 = (const float*)d_in[23];
    const float* b3  = (const float*)d_in[24];

    const int* srcp = ei;
    const int* dstp = ei + EE;

    // ---- workspace layout (~50 MB) ----
    char* w = (char*)d_ws;
    size_t off = 0;
    auto alloc = [&](size_t bytes) { char* p = w + off; off += (bytes + 255) & ~size_t(255); return p; };
    int*    rowcnt   = (int*)alloc((size_t)NN * 4);
    int*    rowptr   = (int*)alloc((size_t)(NN + 1) * 4);
    int*    cursor   = (int*)alloc((size_t)NN * 4);
    int*    blocksum = (int*)alloc(256 * 4);
    uint4*  ea_arr   = (uint4*)alloc((size_t)(EE + NN) * 16);
    int*    src_arr  = (int*)alloc((size_t)(EE + NN) * 4);
    __half* xlbuf    = (__half*)alloc((size_t)NN * 128 * 2);
    __half* xrbuf    = (__half*)alloc((size_t)NN * 128 * 2);
    __half* hA       = (__half*)alloc((size_t)NN * 32 * 2);
    __half* hB       = (__half*)alloc((size_t)NN * 128 * 2);

    int nb = cdiv(NN, 256);

    // ---- CSR build (self-loop in front slot of each row) ----
    hipMemsetAsync(rowcnt, 0, (size_t)NN * 4, stream);
    hist_kernel<<<cdiv(EE / 4, 256), 256, 0, stream>>>((const int4*)dstp, rowcnt, EE / 4);
    scana_kernel<<<nb, 256, 0, stream>>>(rowcnt, blocksum, NN);
    scanb_kernel<<<nb, 256, 0, stream>>>(rowcnt, blocksum, nb, rowptr, cursor, src_arr, NN);
    scatter_kernel<<<cdiv(EE, 256), 256, 0, stream>>>(
        srcp, dstp, eatt, cursor, ea_arr, src_arr, EE);

    // ---- node_linear layer 1 ----
    nl1_kernel<<<cdiv(NN, 8), 256, 0, stream>>>(
        x, Wl1, bl1, Wr1, br1, xlbuf, xrbuf, NN);

    // ---- layer 1 aggregation: H=4, C=8 (CT=32, 2 chains/node, fused loop_sea) ----
    agg32_kernel<8, true, true, __half><<<cdiv(NN, 8), 256, 0, stream>>>(
        rowptr, ea_arr, src_arr, xlbuf, xrbuf, We1, att1, b1, hA, NN);

    // ---- layer 2: IN=32 -> H=4, C=32 (CT=128), residual fused into nlh2 ----
    nlh2_res_kernel<32><<<cdiv(NN, 32), 256, 0, stream>>>(
        hA, Wl2, bl2, Wr2, br2, Rw2, b2, xlbuf, xrbuf, hB, NN);
    agg128_kernel<true, true><<<cdiv(NN, 4), 256, 0, stream>>>(
        rowptr, ea_arr, src_arr, xlbuf, xrbuf, We2, att2, b2, hB, NN);

    // ---- layer 3: IN=128 -> H=1, C=32 (CT=32, 2 chains/node) ----
    node_linear_h_kernel<128, 32, 64><<<cdiv(NN, 64), 256, 0, stream>>>(
        hB, Wl3, bl3, Wr3, br3, xlbuf, xrbuf, NN);
    agg32_kernel<32, false, false, float><<<cdiv(NN, 8), 256, 0, stream>>>(
        rowptr, ea_arr, src_arr, xlbuf, xrbuf, We3, att3, b3,
        (float*)d_out, NN);
}